// Round 1
// baseline (7757.288 us; speedup 1.0000x reference)
//
#include <hip/hip_runtime.h>
#include <stdint.h>

// ---------------------------------------------------------------------------
// DecoderRnn: 2-layer LSTM (B=32, H=512) over T=64 steps + vocab softmax (V=32000)
//   K1 k_init  : init h1/h2 state double-buffers, rowsum, sync counter
//   K2 k_wcvt  : W_out f32 -> bf16 (raw bits) for MFMA
//   K3 k_xg1   : Xg1T[t][j][b] = emb(x_t)@W_ih1^T + b_ih1 + b_hh1   (f32)
//   K4 k_serial: 64-step recurrence, 256 persistent WGs, custom grid sync
//                (2 syncs/step), f32 VALU, h staged in LDS w/ XOR swizzle
//   K5 k_vocab : unnormalized probs = exp(H2@W_out^T + b_out), bf16 MFMA
//                16x16x32, fused exp + atomic per-row sums
//   K6 k_scale : probs /= rowsum
// ---------------------------------------------------------------------------

constexpr int kH = 512;
constexpr int kB = 32;
constexpr int kT = 64;
constexpr int kV = 32000;
constexpr int kG = 2048;   // 4*kH gates
constexpr int kNWG = 256;  // serial-kernel workgroups (1 per CU)

typedef __attribute__((ext_vector_type(4))) float f4;
typedef __attribute__((ext_vector_type(8))) short short8;

struct us4 { unsigned short x, y, z, w; };

__device__ inline unsigned short f2bf(float x) {
  union { float f; unsigned u; } c; c.f = x;
  unsigned r = c.u + 0x7fffu + ((c.u >> 16) & 1u);   // RNE to bf16
  return (unsigned short)(r >> 16);
}
__device__ inline float sigm(float x) { return 1.0f / (1.0f + expf(-x)); }

// ---------------------------------------------------------------------- K1
__global__ void k_init(const float* __restrict__ hiddens,
                       float* __restrict__ h1g, float* __restrict__ h2g,
                       float* __restrict__ rowsum, unsigned* __restrict__ cnt) {
  int id = blockIdx.x * 256 + threadIdx.x;
  if (id < 4096) {                          // 16384 floats as f4
    ((f4*)(h1g + 16384))[id] = ((const f4*)hiddens)[id];  // buf1 = h1[-1]
    f4 z = {0.f, 0.f, 0.f, 0.f};
    ((f4*)(h2g + 16384))[id] = z;                          // buf1 = h2[-1]=0
  }
  int r = id - 4096;
  if (r >= 0 && r < kG) rowsum[r] = 0.f;
  if (id == 4096 + kG) *cnt = 0u;
}

// ---------------------------------------------------------------------- K2
__global__ void k_wcvt(const float* __restrict__ W, unsigned short* __restrict__ Wu) {
  const int total = kV * kH / 4;   // 4,096,000 float4s
  for (int i = blockIdx.x * blockDim.x + threadIdx.x; i < total;
       i += gridDim.x * blockDim.x) {
    f4 v = ((const f4*)W)[i];
    us4 o = {f2bf(v.x), f2bf(v.y), f2bf(v.z), f2bf(v.w)};
    ((us4*)Wu)[i] = o;
  }
}

// ---------------------------------------------------------------------- K3
// grid (t=64, jb=32); WG: 64 gate-rows x 32 batch. X[t] staged in LDS (64KB).
__global__ __launch_bounds__(256) void k_xg1(
    const int* __restrict__ inputs, const int* __restrict__ tseq,
    const float* __restrict__ emb, const float* __restrict__ Wih1,
    const float* __restrict__ bih1, const float* __restrict__ bhh1,
    float* __restrict__ Xg1T) {
  __shared__ float Xs[kB * kH];   // exactly 64 KiB
  int tid = threadIdx.x;
  int t = blockIdx.x, jb = blockIdx.y;
  for (int i = tid; i < kB * kH / 4; i += 256) {
    int b = i >> 7;
    int tok = (t == 0) ? inputs[b] : tseq[b * kT + (t - 1)];
    ((f4*)Xs)[i] = ((const f4*)(emb + (size_t)tok * kH))[i & 127];
  }
  __syncthreads();
  int j2 = tid & 31, bq = tid >> 5;
  int j0 = jb * 64 + j2 * 2;
  int b0 = bq * 4;
  const f4* w0 = (const f4*)(Wih1 + (size_t)j0 * kH);
  const f4* w1 = (const f4*)(Wih1 + (size_t)(j0 + 1) * kH);
  float acc0[4] = {0.f, 0.f, 0.f, 0.f};
  float acc1[4] = {0.f, 0.f, 0.f, 0.f};
  #pragma unroll 2
  for (int k4 = 0; k4 < 128; ++k4) {
    f4 a0 = w0[k4], a1 = w1[k4];
    #pragma unroll
    for (int bb = 0; bb < 4; ++bb) {
      f4 x = ((const f4*)Xs)[(b0 + bb) * 128 + k4];   // broadcast across j lanes
      acc0[bb] += a0.x * x.x + a0.y * x.y + a0.z * x.z + a0.w * x.w;
      acc1[bb] += a1.x * x.x + a1.y * x.y + a1.z * x.z + a1.w * x.w;
    }
  }
  float bj0 = bih1[j0] + bhh1[j0];
  float bj1 = bih1[j0 + 1] + bhh1[j0 + 1];
  f4 s0 = {acc0[0] + bj0, acc0[1] + bj0, acc0[2] + bj0, acc0[3] + bj0};
  f4 s1 = {acc1[0] + bj1, acc1[1] + bj1, acc1[2] + bj1, acc1[3] + bj1};
  float* o = Xg1T + ((size_t)t * kG + j0) * kB + b0;
  *(f4*)o = s0;
  *(f4*)(o + kB) = s1;
}

// ---------------------------------------------------------------------- K4
__device__ inline void gsync(unsigned* cnt, unsigned target) {
  __syncthreads();
  if (threadIdx.x == 0) {
    __hip_atomic_fetch_add(cnt, 1u, __ATOMIC_RELEASE, __HIP_MEMORY_SCOPE_AGENT);
    while (__hip_atomic_load(cnt, __ATOMIC_ACQUIRE, __HIP_MEMORY_SCOPE_AGENT) < target)
      __builtin_amdgcn_s_sleep(1);
  }
  __syncthreads();
  __threadfence();   // belt-and-braces: invalidate stale cached lines for all lanes
}

// Stage 32x512 f32 h-state into LDS, XOR-swizzled at float4 granularity so the
// 8 distinct b-rows read per wave land on disjoint bank quads (conflict-free).
__device__ inline void stageH(float* __restrict__ smem, const float* __restrict__ src) {
  const f4* s4 = (const f4*)src;
  #pragma unroll
  for (int i = 0; i < 16; ++i) {
    int idx = threadIdx.x + (i << 8);       // 0..4095 float4s
    int b = idx >> 7, k4 = idx & 127;
    ((f4*)smem)[(b << 7) + (k4 ^ (b & 7))] = s4[idx];
  }
}

__global__ __launch_bounds__(256) void k_serial(
    const float* __restrict__ Xg1T, const float* __restrict__ Whh1,
    const float* __restrict__ Wih2, const float* __restrict__ Whh2,
    const float* __restrict__ bih2, const float* __restrict__ bhh2,
    float* __restrict__ h1g, float* __restrict__ h2g,
    unsigned short* __restrict__ H2u, float* __restrict__ outTail,
    unsigned* __restrict__ cnt) {
  __shared__ float smem[kB * kH];   // exactly 64 KiB; doubles as gate buffer
  const int tid = threadIdx.x, w = blockIdx.x;
  const int b = tid >> 3, jj = tid & 7, gg = jj >> 1, nl = jj & 1;
  const int n = (w << 1) + nl;      // this WG owns hidden columns {2w, 2w+1}
  const int j = (gg << 9) + n;      // gate row: gate*512 + n
  const float bias2 = bih2[j] + bhh2[j];
  const f4* w1r = (const f4*)(Whh1 + (size_t)j * kH);
  const f4* w2a = (const f4*)(Wih2 + (size_t)j * kH);
  const f4* w2b = (const f4*)(Whh2 + (size_t)j * kH);
  const int cb = tid >> 1, cn = (w << 1) + (tid & 1);  // combine-thread (tid<64)
  float c1 = 0.f, c2 = 0.f;                             // cell state in registers
  unsigned target = 0;
  const int boff = b << 7, bsw = b & 7;

  stageH(smem, h1g + 16384);   // h1[-1] = hiddens
  __syncthreads();
  for (int t = 0; t < kT; ++t) {
    float* h1w = h1g + (t & 1) * 16384;          // h1[t] buffer
    const float* h1r = h1w;
    float* h2w = h2g + (t & 1) * 16384;          // h2[t] buffer
    const float* h2r = h2g + ((t + 1) & 1) * 16384;  // h2[t-1] buffer
    // ---- layer-1 gates: Whh1[j].h1[t-1] + Xg1T ----
    float xg = Xg1T[((size_t)t * kG + j) * kB + b];
    f4 acc = {0.f, 0.f, 0.f, 0.f};
    #pragma unroll 8
    for (int k4 = 0; k4 < 128; ++k4)
      acc += w1r[k4] * ((const f4*)smem)[boff + (k4 ^ bsw)];
    float g1 = acc.x + acc.y + acc.z + acc.w + xg;
    __syncthreads();
    smem[jj * kB + b] = g1;        // gate exchange (aliases h-buffer; restaged below)
    __syncthreads();
    if (tid < 64) {
      int q = tid & 1;
      float i_ = sigm(smem[q * kB + cb]);
      float f_ = sigm(smem[(2 + q) * kB + cb]);
      float G_ = tanhf(smem[(4 + q) * kB + cb]);
      float o_ = sigm(smem[(6 + q) * kB + cb]);
      c1 = f_ * c1 + i_ * G_;
      float h = o_ * tanhf(c1);
      h1w[cb * kH + cn] = h;
      if (t == kT - 1) outTail[cb * kH + cn] = h;   // output 1: final h1 (exact f32)
    }
    gsync(cnt, target += kNWG);    // publish h1[t]
    stageH(smem, h1r);             // h1[t]
    __syncthreads();
    // ---- layer-2 gates: Wih2[j].h1[t] + Whh2[j].h2[t-1] + bias2 ----
    f4 a2 = {0.f, 0.f, 0.f, 0.f};
    #pragma unroll 8
    for (int k4 = 0; k4 < 128; ++k4)
      a2 += w2a[k4] * ((const f4*)smem)[boff + (k4 ^ bsw)];
    __syncthreads();
    stageH(smem, h2r);             // h2[t-1]
    __syncthreads();
    #pragma unroll 8
    for (int k4 = 0; k4 < 128; ++k4)
      a2 += w2b[k4] * ((const f4*)smem)[boff + (k4 ^ bsw)];
    float g2 = a2.x + a2.y + a2.z + a2.w + bias2;
    __syncthreads();
    smem[jj * kB + b] = g2;
    __syncthreads();
    if (tid < 64) {
      int q = tid & 1;
      float i_ = sigm(smem[q * kB + cb]);
      float f_ = sigm(smem[(2 + q) * kB + cb]);
      float G_ = tanhf(smem[(4 + q) * kB + cb]);
      float o_ = sigm(smem[(6 + q) * kB + cb]);
      c2 = f_ * c2 + i_ * G_;
      float h = o_ * tanhf(c2);
      h2w[cb * kH + cn] = h;
      H2u[((size_t)t * kB + cb) * kH + cn] = f2bf(h);   // bf16 copy for vocab GEMM
    }
    gsync(cnt, target += kNWG);    // publish h2[t]
    stageH(smem, h1r);             // restore h1[t] for next step's gates1
    __syncthreads();
  }
}

// ---------------------------------------------------------------------- K5
// C = H2(2048x512) @ Wout^T(512x32000), bf16 MFMA 16x16x32 (verified layouts:
// A[m=lane&15][k=quad*8+j], B[k][n=lane&15], C col=lane&15 row=quad*4+reg).
// Fused: p = exp(logit + b_out) -> d_out, plus atomic per-row partial sums.
__global__ __launch_bounds__(256) void k_vocab(
    const unsigned short* __restrict__ H2u, const unsigned short* __restrict__ Wu,
    const float* __restrict__ bout, float* __restrict__ out,
    float* __restrict__ rowsum) {
  const int lane = threadIdx.x & 63, wv = threadIdx.x >> 6;
  const int wm = wv >> 1, wn = wv & 1;
  const int r16 = lane & 15, quad = lane >> 4;
  const int mBase = blockIdx.y * 128 + wm * 64;
  const int nBase = blockIdx.x * 128 + wn * 64;
  f4 acc[4][4];
  #pragma unroll
  for (int a = 0; a < 4; ++a)
    #pragma unroll
    for (int c = 0; c < 4; ++c) acc[a][c] = (f4){0.f, 0.f, 0.f, 0.f};
  for (int kb = 0; kb < 16; ++kb) {
    int k0 = kb * 32 + quad * 8;
    short8 af[4], bf[4];
    #pragma unroll
    for (int mt = 0; mt < 4; ++mt)
      af[mt] = *(const short8*)(H2u + (size_t)(mBase + mt * 16 + r16) * kH + k0);
    #pragma unroll
    for (int nt = 0; nt < 4; ++nt)
      bf[nt] = *(const short8*)(Wu + (size_t)(nBase + nt * 16 + r16) * kH + k0);
    #pragma unroll
    for (int mt = 0; mt < 4; ++mt)
      #pragma unroll
      for (int nt = 0; nt < 4; ++nt)
        acc[mt][nt] = __builtin_amdgcn_mfma_f32_16x16x32_bf16(
            af[mt], bf[nt], acc[mt][nt], 0, 0, 0);
  }
  float bo[4];
  #pragma unroll
  for (int nt = 0; nt < 4; ++nt) bo[nt] = bout[nBase + nt * 16 + r16];
  #pragma unroll
  for (int mt = 0; mt < 4; ++mt) {
    #pragma unroll
    for (int r = 0; r < 4; ++r) {
      int row = mBase + mt * 16 + quad * 4 + r;
      float s = 0.f;
      #pragma unroll
      for (int nt = 0; nt < 4; ++nt) {
        float p = __expf(acc[mt][nt][r] + bo[nt]);
        out[(size_t)row * kV + nBase + nt * 16 + r16] = p;
        s += p;
      }
      s += __shfl_xor(s, 1);
      s += __shfl_xor(s, 2);
      s += __shfl_xor(s, 4);
      s += __shfl_xor(s, 8);
      if (r16 == 0) atomicAdd(&rowsum[row], s);
    }
  }
}

// ---------------------------------------------------------------------- K6
__global__ void k_scale(float* __restrict__ out, const float* __restrict__ rowsum) {
  const unsigned total4 = (unsigned)(kT * kB) * (kV / 4);   // 16,384,000
  unsigned stride = gridDim.x * blockDim.x;
  for (unsigned i = blockIdx.x * blockDim.x + threadIdx.x; i < total4; i += stride) {
    unsigned row = i / (kV / 4);            // compiler magic-muls the constant
    float inv = 1.0f / rowsum[row];
    f4 v = ((const f4*)out)[i];
    ((f4*)out)[i] = v * inv;
  }
}

// ---------------------------------------------------------------------------
extern "C" void kernel_launch(void* const* d_in, const int* in_sizes, int n_in,
                              void* d_out, int out_size, void* d_ws, size_t ws_size,
                              hipStream_t stream) {
  (void)in_sizes; (void)n_in; (void)out_size; (void)ws_size;
  const int*   inputs  = (const int*)d_in[0];
  const float* hiddens = (const float*)d_in[1];
  const int*   tseq    = (const int*)d_in[2];
  // d_in[3] = use_tf (unused by reference)
  const float* emb  = (const float*)d_in[4];
  const float* Wih1 = (const float*)d_in[5];
  const float* Whh1 = (const float*)d_in[6];
  const float* bih1 = (const float*)d_in[7];
  const float* bhh1 = (const float*)d_in[8];
  const float* Wih2 = (const float*)d_in[9];
  const float* Whh2 = (const float*)d_in[10];
  const float* bih2 = (const float*)d_in[11];
  const float* bhh2 = (const float*)d_in[12];
  const float* Wout = (const float*)d_in[13];
  const float* bout = (const float*)d_in[14];

  // workspace layout (float offsets); total ~49.5 MiB
  float* ws = (float*)d_ws;
  float* Xg1T = ws;                                   //  4,194,304 f
  float* h1g  = ws + 4194304;                         //  2 x 16384 f
  float* h2g  = ws + 4227072;                         //  2 x 16384 f
  unsigned short* H2u = (unsigned short*)(ws + 4259840);   // 1,048,576 bf16
  unsigned short* Wu  = (unsigned short*)(ws + 4784128);   // 16,384,000 bf16
  float* rowsum = ws + 12976128;                      //  2048 f
  unsigned* cnt = (unsigned*)(ws + 12978176);         //  sync counter

  float* out = (float*)d_out;
  float* outTail = out + (size_t)kT * kB * kV;        // final h1 (32x512)

  hipLaunchKernelGGL(k_init, dim3(25), dim3(256), 0, stream,
                     hiddens, h1g, h2g, rowsum, cnt);
  hipLaunchKernelGGL(k_wcvt, dim3(1024), dim3(256), 0, stream, Wout, Wu);
  hipLaunchKernelGGL(k_xg1, dim3(64, 32), dim3(256), 0, stream,
                     inputs, tseq, emb, Wih1, bih1, bhh1, Xg1T);
  hipLaunchKernelGGL(k_serial, dim3(kNWG), dim3(256), 0, stream,
                     Xg1T, Whh1, Wih2, Whh2, bih2, bhh2,
                     h1g, h2g, H2u, outTail, cnt);
  hipLaunchKernelGGL(k_vocab, dim3(kV / 128, 16), dim3(256), 0, stream,
                     H2u, Wu, bout, out, rowsum);
  hipLaunchKernelGGL(k_scale, dim3(2048), dim3(256), 0, stream, out, rowsum);
}

// Round 2
// 4679.710 us; speedup vs baseline: 1.6576x; 1.6576x over previous
//
#include <hip/hip_runtime.h>
#include <stdint.h>

// ---------------------------------------------------------------------------
// DecoderRnn: 2-layer LSTM (B=32, H=512) over T=64 steps + vocab softmax (V=32000)
//   K1 k_init  : zero h2 double-buffer, rowsum, barrier flags
//   K2 k_wcvt  : W_out f32 -> bf16 for MFMA
//   K3 k_xg1   : Xg1T[t][j][b] = emb(x_t)@W_ih1^T + b_ih1 + b_hh1   (f32)
//   K4 k_serial: 64-step recurrence, 256 persistent WGs (1/CU).
//                Cross-WG h exchange via relaxed agent-scope u64 atomics
//                (L3-coherent, no cache-flush fences). Barrier = per-WG flag
//                array: release-store post (writeback only), relaxed polls
//                (NO buffer_inv in the spin loop — round-1's 53us/sync bug).
//                Gate combine via in-wave shuffles; 2 LDS stages/step.
//   K5 k_vocab : unnormalized probs = exp(H2@W_out^T + b_out), bf16 MFMA
//   K6 k_scale : probs /= rowsum
// ---------------------------------------------------------------------------

constexpr int kH = 512;
constexpr int kB = 32;
constexpr int kT = 64;
constexpr int kV = 32000;
constexpr int kG = 2048;   // 4*kH gates
constexpr int kNWG = 256;  // serial-kernel workgroups (1 per CU)

typedef __attribute__((ext_vector_type(4))) float f4;
typedef __attribute__((ext_vector_type(8))) short short8;
typedef unsigned long long u64;

struct us4 { unsigned short x, y, z, w; };

__device__ inline unsigned short f2bf(float x) {
  union { float f; unsigned u; } c; c.f = x;
  unsigned r = c.u + 0x7fffu + ((c.u >> 16) & 1u);   // RNE to bf16
  return (unsigned short)(r >> 16);
}
__device__ inline float sigm(float x) { return 1.0f / (1.0f + expf(-x)); }

// ---------------------------------------------------------------------- K1
__global__ void k_init(float* __restrict__ buf2, float* __restrict__ rowsum,
                       int* __restrict__ flags /* 512 ints: A then B */) {
  int id = blockIdx.x * 256 + threadIdx.x;
  f4 z = {0.f, 0.f, 0.f, 0.f};
  if (id < 8192) ((f4*)buf2)[id] = z;       // both h2 buffers = 0
  if (id < 2048) rowsum[id] = 0.f;
  if (id < 512)  flags[id] = 0;
}

// ---------------------------------------------------------------------- K2
__global__ void k_wcvt(const float* __restrict__ W, unsigned short* __restrict__ Wu) {
  const int total = kV * kH / 4;
  for (int i = blockIdx.x * blockDim.x + threadIdx.x; i < total;
       i += gridDim.x * blockDim.x) {
    f4 v = ((const f4*)W)[i];
    us4 o = {f2bf(v.x), f2bf(v.y), f2bf(v.z), f2bf(v.w)};
    ((us4*)Wu)[i] = o;
  }
}

// ---------------------------------------------------------------------- K3
__global__ __launch_bounds__(256) void k_xg1(
    const int* __restrict__ inputs, const int* __restrict__ tseq,
    const float* __restrict__ emb, const float* __restrict__ Wih1,
    const float* __restrict__ bih1, const float* __restrict__ bhh1,
    float* __restrict__ Xg1T) {
  __shared__ float Xs[kB * kH];   // 64 KiB
  int tid = threadIdx.x;
  int t = blockIdx.x, jb = blockIdx.y;
  for (int i = tid; i < kB * kH / 4; i += 256) {
    int b = i >> 7;
    int tok = (t == 0) ? inputs[b] : tseq[b * kT + (t - 1)];
    ((f4*)Xs)[i] = ((const f4*)(emb + (size_t)tok * kH))[i & 127];
  }
  __syncthreads();
  int j2 = tid & 31, bq = tid >> 5;
  int j0 = jb * 64 + j2 * 2;
  int b0 = bq * 4;
  const f4* w0 = (const f4*)(Wih1 + (size_t)j0 * kH);
  const f4* w1 = (const f4*)(Wih1 + (size_t)(j0 + 1) * kH);
  float acc0[4] = {0.f, 0.f, 0.f, 0.f};
  float acc1[4] = {0.f, 0.f, 0.f, 0.f};
  #pragma unroll 2
  for (int k4 = 0; k4 < 128; ++k4) {
    f4 a0 = w0[k4], a1 = w1[k4];
    #pragma unroll
    for (int bb = 0; bb < 4; ++bb) {
      f4 x = ((const f4*)Xs)[(b0 + bb) * 128 + k4];
      acc0[bb] += a0.x * x.x + a0.y * x.y + a0.z * x.z + a0.w * x.w;
      acc1[bb] += a1.x * x.x + a1.y * x.y + a1.z * x.z + a1.w * x.w;
    }
  }
  float bj0 = bih1[j0] + bhh1[j0];
  float bj1 = bih1[j0 + 1] + bhh1[j0 + 1];
  f4 s0 = {acc0[0] + bj0, acc0[1] + bj0, acc0[2] + bj0, acc0[3] + bj0};
  f4 s1 = {acc1[0] + bj1, acc1[1] + bj1, acc1[2] + bj1, acc1[3] + bj1};
  float* o = Xg1T + ((size_t)t * kG + j0) * kB + b0;
  *(f4*)o = s0;
  *(f4*)(o + kB) = s1;
}

// ---------------------------------------------------------------------- K4
// Barrier: post = release-store of my flag (wb only, no inv — keeps weights
// L2-resident); wait = 256 threads poll 256 flags with RELAXED coherent loads.
__device__ inline void post(int* flags, int v) {
  __syncthreads();   // every wave drains vmcnt before s_barrier -> stores done
  if (threadIdx.x == 0)
    __hip_atomic_store(&flags[blockIdx.x], v, __ATOMIC_RELEASE,
                       __HIP_MEMORY_SCOPE_AGENT);
}
__device__ inline void waitf(int* flags, int v) {
  while (__hip_atomic_load(&flags[threadIdx.x], __ATOMIC_RELAXED,
                           __HIP_MEMORY_SCOPE_AGENT) < v)
    __builtin_amdgcn_s_sleep(2);
  __syncthreads();
}

// Stage 32x512 f32 h-state into LDS (f4 XOR-swizzle: the 8 b-rows a wave
// reads per ds_read_b128 land on disjoint bank quads). Coherent variant uses
// relaxed agent u64 loads (bypasses stale L1 / non-coherent per-XCD L2).
__device__ inline void stage_coh(float* __restrict__ smem, const float* src) {
  const u64* s8 = (const u64*)src;
  #pragma unroll
  for (int i = 0; i < 16; ++i) {
    int idx = threadIdx.x + (i << 8);          // f4 index 0..4095
    u64 lo = __hip_atomic_load((u64*)&s8[idx * 2], __ATOMIC_RELAXED,
                               __HIP_MEMORY_SCOPE_AGENT);
    u64 hi = __hip_atomic_load((u64*)&s8[idx * 2 + 1], __ATOMIC_RELAXED,
                               __HIP_MEMORY_SCOPE_AGENT);
    int b_ = idx >> 7, k4 = idx & 127;
    union { u64 u[2]; f4 v; } cv; cv.u[0] = lo; cv.u[1] = hi;
    ((f4*)smem)[(b_ << 7) + (k4 ^ (b_ & 7))] = cv.v;
  }
}
__device__ inline void stage_plain(float* __restrict__ smem,
                                   const float* __restrict__ src) {
  const f4* s4 = (const f4*)src;
  #pragma unroll
  for (int i = 0; i < 16; ++i) {
    int idx = threadIdx.x + (i << 8);
    int b_ = idx >> 7, k4 = idx & 127;
    ((f4*)smem)[(b_ << 7) + (k4 ^ (b_ & 7))] = s4[idx];
  }
}

__global__ __launch_bounds__(256) void k_serial(
    const float* __restrict__ hiddens, const float* __restrict__ Xg1T,
    const float* __restrict__ Whh1, const float* __restrict__ Wih2,
    const float* __restrict__ Whh2, const float* __restrict__ bih2,
    const float* __restrict__ bhh2,
    float* __restrict__ buf1, float* __restrict__ buf2,
    unsigned short* __restrict__ H2u, float* __restrict__ outTail,
    int* __restrict__ flagsA, int* __restrict__ flagsB) {
  __shared__ float smem[kB * kH];   // exactly 64 KiB
  const int tid = threadIdx.x, w = blockIdx.x;
  const int lane = tid & 63;
  const int b = tid >> 3, jj = tid & 7, gg = jj >> 1, nl = jj & 1;
  const int n = (w << 1) + nl;      // this WG owns hidden columns {2w, 2w+1}
  const int j = (gg << 9) + n;      // gate row: gate*512 + n
  const float bias2 = bih2[j] + bhh2[j];
  const f4* w1r = (const f4*)(Whh1 + (size_t)j * kH);
  const f4* w2a = (const f4*)(Wih2 + (size_t)j * kH);
  const f4* w2b = (const f4*)(Whh2 + (size_t)j * kH);
  const bool holder = (jj < 2);     // thread (b,nl) carries c-state for col n
  const int srcbase = (lane & 56) | (lane & 1);
  float c1 = 0.f, c2 = 0.f;
  const int boff = b << 7, bsw = b & 7;

  stage_plain(smem, hiddens);       // h1[-1]
  __syncthreads();
  for (int t = 0; t < kT; ++t) {
    float* h1w = buf1 + (t & 1) * 16384;
    float* h2w = buf2 + (t & 1) * 16384;
    const float* h2r = buf2 + ((t + 1) & 1) * 16384;   // h2[t-1]

    // ---- layer-1 gates: Whh1[j].h1[t-1] + Xg1T (x-term incl. biases) ----
    float xg = Xg1T[((size_t)t * kG + j) * kB + b];
    f4 acc = {0.f, 0.f, 0.f, 0.f};
    #pragma unroll 8
    for (int k4 = 0; k4 < 128; ++k4)
      acc += w1r[k4] * ((const f4*)smem)[boff + (k4 ^ bsw)];
    float g1v = acc.x + acc.y + acc.z + acc.w + xg;
    // in-wave gate combine (gates i,f,g,o for col n are at jj = nl,2+nl,4+nl,6+nl)
    float gi = __shfl(g1v, srcbase);
    float gf = __shfl(g1v, srcbase + 2);
    float gG = __shfl(g1v, srcbase + 4);
    float go = __shfl(g1v, srcbase + 6);
    float hnew = 0.f;
    if (holder) {
      float i_ = sigm(gi), f_ = sigm(gf), G_ = tanhf(gG), o_ = sigm(go);
      c1 = f_ * c1 + i_ * G_;
      hnew = o_ * tanhf(c1);
    }
    float hp = __shfl(hnew, lane + 1);
    if (jj == 0) {
      union { float f[2]; u64 u; } pk; pk.f[0] = hnew; pk.f[1] = hp;
      __hip_atomic_store((u64*)(h1w + b * kH + 2 * w), pk.u, __ATOMIC_RELAXED,
                         __HIP_MEMORY_SCOPE_AGENT);
      if (t == kT - 1) *(u64*)(outTail + b * kH + 2 * w) = pk.u;  // output 1
    }
    post(flagsA, t + 1);            // publish h1[t] (syncthreads drains stores)
    waitf(flagsB, t);               // h2[t-1] visible from all WGs

    stage_coh(smem, h2r);           // h2[t-1]
    __syncthreads();
    // ---- layer-2 partial: Whh2[j].h2[t-1] (overlaps other WGs' A-posts) ----
    f4 a2 = {0.f, 0.f, 0.f, 0.f};
    #pragma unroll 8
    for (int k4 = 0; k4 < 128; ++k4)
      a2 += w2b[k4] * ((const f4*)smem)[boff + (k4 ^ bsw)];
    waitf(flagsA, t + 1);           // h1[t] visible from all WGs

    stage_coh(smem, h1w);           // h1[t] (stays staged for next step's layer-1)
    __syncthreads();
    #pragma unroll 8
    for (int k4 = 0; k4 < 128; ++k4)
      a2 += w2a[k4] * ((const f4*)smem)[boff + (k4 ^ bsw)];
    float g2v = a2.x + a2.y + a2.z + a2.w + bias2;
    float g2i = __shfl(g2v, srcbase);
    float g2f = __shfl(g2v, srcbase + 2);
    float g2G = __shfl(g2v, srcbase + 4);
    float g2o = __shfl(g2v, srcbase + 6);
    float h2new = 0.f;
    if (holder) {
      float i_ = sigm(g2i), f_ = sigm(g2f), G_ = tanhf(g2G), o_ = sigm(g2o);
      c2 = f_ * c2 + i_ * G_;
      h2new = o_ * tanhf(c2);
    }
    float h2p = __shfl(h2new, lane + 1);
    if (jj == 0) {
      union { float f[2]; u64 u; } pk; pk.f[0] = h2new; pk.f[1] = h2p;
      __hip_atomic_store((u64*)(h2w + b * kH + 2 * w), pk.u, __ATOMIC_RELAXED,
                         __HIP_MEMORY_SCOPE_AGENT);
      unsigned bf2 = ((unsigned)f2bf(h2p) << 16) | f2bf(h2new);
      *(unsigned*)(H2u + ((size_t)t * kB + b) * kH + 2 * w) = bf2;  // bf16 pair
    }
    post(flagsB, t + 1);            // publish h2[t]
    // smem still holds h1[t] -> next iteration's layer-1 needs no restage
  }
}

// ---------------------------------------------------------------------- K5
__global__ __launch_bounds__(256) void k_vocab(
    const unsigned short* __restrict__ H2u, const unsigned short* __restrict__ Wu,
    const float* __restrict__ bout, float* __restrict__ out,
    float* __restrict__ rowsum) {
  const int lane = threadIdx.x & 63, wv = threadIdx.x >> 6;
  const int wm = wv >> 1, wn = wv & 1;
  const int r16 = lane & 15, quad = lane >> 4;
  const int mBase = blockIdx.y * 128 + wm * 64;
  const int nBase = blockIdx.x * 128 + wn * 64;
  f4 acc[4][4];
  #pragma unroll
  for (int a = 0; a < 4; ++a)
    #pragma unroll
    for (int c = 0; c < 4; ++c) acc[a][c] = (f4){0.f, 0.f, 0.f, 0.f};
  for (int kb = 0; kb < 16; ++kb) {
    int k0 = kb * 32 + quad * 8;
    short8 af[4], bf[4];
    #pragma unroll
    for (int mt = 0; mt < 4; ++mt)
      af[mt] = *(const short8*)(H2u + (size_t)(mBase + mt * 16 + r16) * kH + k0);
    #pragma unroll
    for (int nt = 0; nt < 4; ++nt)
      bf[nt] = *(const short8*)(Wu + (size_t)(nBase + nt * 16 + r16) * kH + k0);
    #pragma unroll
    for (int mt = 0; mt < 4; ++mt)
      #pragma unroll
      for (int nt = 0; nt < 4; ++nt)
        acc[mt][nt] = __builtin_amdgcn_mfma_f32_16x16x32_bf16(
            af[mt], bf[nt], acc[mt][nt], 0, 0, 0);
  }
  float bo[4];
  #pragma unroll
  for (int nt = 0; nt < 4; ++nt) bo[nt] = bout[nBase + nt * 16 + r16];
  #pragma unroll
  for (int mt = 0; mt < 4; ++mt) {
    #pragma unroll
    for (int r = 0; r < 4; ++r) {
      int row = mBase + mt * 16 + quad * 4 + r;
      float s = 0.f;
      #pragma unroll
      for (int nt = 0; nt < 4; ++nt) {
        float p = __expf(acc[mt][nt][r] + bo[nt]);
        out[(size_t)row * kV + nBase + nt * 16 + r16] = p;
        s += p;
      }
      s += __shfl_xor(s, 1);
      s += __shfl_xor(s, 2);
      s += __shfl_xor(s, 4);
      s += __shfl_xor(s, 8);
      if (r16 == 0) atomicAdd(&rowsum[row], s);
    }
  }
}

// ---------------------------------------------------------------------- K6
__global__ void k_scale(float* __restrict__ out, const float* __restrict__ rowsum) {
  const unsigned total4 = (unsigned)(kT * kB) * (kV / 4);
  unsigned stride = gridDim.x * blockDim.x;
  for (unsigned i = blockIdx.x * blockDim.x + threadIdx.x; i < total4; i += stride) {
    unsigned row = i / (kV / 4);
    float inv = 1.0f / rowsum[row];
    f4 v = ((const f4*)out)[i];
    ((f4*)out)[i] = v * inv;
  }
}

// ---------------------------------------------------------------------------
extern "C" void kernel_launch(void* const* d_in, const int* in_sizes, int n_in,
                              void* d_out, int out_size, void* d_ws, size_t ws_size,
                              hipStream_t stream) {
  (void)in_sizes; (void)n_in; (void)out_size; (void)ws_size;
  const int*   inputs  = (const int*)d_in[0];
  const float* hiddens = (const float*)d_in[1];
  const int*   tseq    = (const int*)d_in[2];
  const float* emb  = (const float*)d_in[4];
  const float* Wih1 = (const float*)d_in[5];
  const float* Whh1 = (const float*)d_in[6];
  const float* bih1 = (const float*)d_in[7];
  const float* bhh1 = (const float*)d_in[8];
  const float* Wih2 = (const float*)d_in[9];
  const float* Whh2 = (const float*)d_in[10];
  const float* bih2 = (const float*)d_in[11];
  const float* bhh2 = (const float*)d_in[12];
  const float* Wout = (const float*)d_in[13];
  const float* bout = (const float*)d_in[14];

  // workspace layout (float offsets); ~52 MiB
  float* ws = (float*)d_ws;
  float* Xg1T = ws;                                        //  4,194,304 f
  float* buf1 = ws + 4194304;                              //  2 x 16384 f
  float* buf2 = ws + 4227072;                              //  2 x 16384 f
  unsigned short* H2u = (unsigned short*)(ws + 4259840);   //  1,048,576 bf16
  unsigned short* Wu  = (unsigned short*)(ws + 4784128);   // 16,384,000 bf16
  float* rowsum = ws + 12976128;                           //  2048 f
  int* flags = (int*)(ws + 12978176);                      //  512 ints (A|B)
  int* flagsA = flags;
  int* flagsB = flags + 256;

  float* out = (float*)d_out;
  float* outTail = out + (size_t)kT * kB * kV;             // final h1 (32x512)

  hipLaunchKernelGGL(k_init, dim3(32), dim3(256), 0, stream, buf2, rowsum, flags);
  hipLaunchKernelGGL(k_wcvt, dim3(1024), dim3(256), 0, stream, Wout, Wu);
  hipLaunchKernelGGL(k_xg1, dim3(64, 32), dim3(256), 0, stream,
                     inputs, tseq, emb, Wih1, bih1, bhh1, Xg1T);
  hipLaunchKernelGGL(k_serial, dim3(kNWG), dim3(256), 0, stream,
                     hiddens, Xg1T, Whh1, Wih2, Whh2, bih2, bhh2,
                     buf1, buf2, H2u, outTail, flagsA, flagsB);
  hipLaunchKernelGGL(k_vocab, dim3(kV / 128, 16), dim3(256), 0, stream,
                     H2u, Wu, bout, out, rowsum);
  hipLaunchKernelGGL(k_scale, dim3(2048), dim3(256), 0, stream, out, rowsum);
}